// Round 4
// baseline (503.890 us; speedup 1.0000x reference)
//
#include <hip/hip_runtime.h>
#include <hip/hip_bf16.h>
#include <math.h>

typedef __bf16 bf16;
typedef __bf16 v8bf __attribute__((ext_vector_type(8)));
typedef float f32x4 __attribute__((ext_vector_type(4)));

#define L_SEQ 4096
#define DMODEL 1024
#define NHEADS 16
#define NKV 4
#define DH 64
#define DKV 256   // NKV * DH
#define NEG_BIG (-1e30f)

// Load 8 contiguous elements (element index idx) as bf16x8; F32 = source dtype.
template <bool F32>
__device__ inline v8bf ld8(const void* __restrict__ p, size_t idx) {
    if (F32) {
        const float* f = (const float*)p + idx;
        f32x4 a = *(const f32x4*)f;
        f32x4 c = *(const f32x4*)(f + 4);
        v8bf r;
#pragma unroll
        for (int j = 0; j < 4; j++) { r[j] = (bf16)a[j]; r[j + 4] = (bf16)c[j]; }
        return r;
    }
    return *(const v8bf*)((const bf16*)p + idx);
}

// ---------------------------------------------------------------------------
// NT GEMM: C[M,N] = A[M,K] * B[N,K]^T   (bf16 MFMA, fp32 accum)
// 64x64 tile, BK=64, 4 waves; wave w computes rows [16w,16w+16) x 64 cols.
// ---------------------------------------------------------------------------
template <bool AF32, bool BF32, typename OutT>
__global__ __launch_bounds__(256) void gemm_nt(const void* __restrict__ A,
                                               const void* __restrict__ B,
                                               OutT* __restrict__ C,
                                               int N, int K) {
    __shared__ bf16 As[64][72];   // +8 pad breaks bank aliasing
    __shared__ bf16 Bs[64][72];
    const int tid  = threadIdx.x;
    const int wave = tid >> 6;
    const int lane = tid & 63;
    const int quad = lane >> 4;
    const int l16  = lane & 15;
    const int bm = blockIdx.y * 64;
    const int bn = blockIdx.x * 64;

    f32x4 acc[4];
#pragma unroll
    for (int n = 0; n < 4; n++) acc[n] = (f32x4){0.f, 0.f, 0.f, 0.f};

    const int r0 = tid >> 3;        // 0..31
    const int cb = (tid & 7) * 8;   // 0,8,..,56

    for (int kt = 0; kt < K; kt += 64) {
        *(v8bf*)&As[r0][cb]      = ld8<AF32>(A, (size_t)(bm + r0) * K + kt + cb);
        *(v8bf*)&As[r0 + 32][cb] = ld8<AF32>(A, (size_t)(bm + r0 + 32) * K + kt + cb);
        *(v8bf*)&Bs[r0][cb]      = ld8<BF32>(B, (size_t)(bn + r0) * K + kt + cb);
        *(v8bf*)&Bs[r0 + 32][cb] = ld8<BF32>(B, (size_t)(bn + r0 + 32) * K + kt + cb);
        __syncthreads();
#pragma unroll
        for (int ks = 0; ks < 64; ks += 32) {
            v8bf a = *(v8bf*)&As[wave * 16 + l16][ks + quad * 8];
#pragma unroll
            for (int n = 0; n < 4; n++) {
                v8bf b = *(v8bf*)&Bs[n * 16 + l16][ks + quad * 8];
                acc[n] = __builtin_amdgcn_mfma_f32_16x16x32_bf16(a, b, acc[n], 0, 0, 0);
            }
        }
        __syncthreads();
    }
#pragma unroll
    for (int n = 0; n < 4; n++)
#pragma unroll
        for (int r = 0; r < 4; r++) {
            int row = bm + wave * 16 + quad * 4 + r;
            int col = bn + n * 16 + l16;
            C[(size_t)row * N + col] = (OutT)acc[n][r];
        }
}

// ---------------------------------------------------------------------------
// Interleaved RoPE in place on bf16 buffer (row layout: [L, N] with 64-wide heads).
// ---------------------------------------------------------------------------
__global__ void rope_kernel(bf16* __restrict__ X, const int* __restrict__ pos,
                            int rows, int pairs_per_row) {
    int idx = blockIdx.x * blockDim.x + threadIdx.x;
    if (idx >= rows * pairs_per_row) return;
    int row = idx / pairs_per_row;
    int pc  = idx - row * pairs_per_row;
    int i   = pc & 31;  // pair index within 64-wide head
    float freq = expf(-(float)(2 * i) * (9.210340371976184f / 64.0f)); // ln(10000)
    float ang  = (float)pos[row] * freq;
    float c = cosf(ang);
    float s = sinf(ang);
    size_t base = (size_t)row * (pairs_per_row * 2) + 2 * pc;
    float e = (float)X[base];
    float o = (float)X[base + 1];
    X[base]     = (bf16)(e * c - o * s);
    X[base + 1] = (bf16)(e * s + o * c);
}

// ---------------------------------------------------------------------------
// Causal flash attention, GQA (16 Q heads / 4 KV heads), Dh=64.
// grid: (L/64, NHEADS). Block = 4 waves; wave w owns Q rows [qb*64+16w, +16).
// Verified equal to naive attention on-device (round 3 bisection).
// ---------------------------------------------------------------------------
__global__ __launch_bounds__(256) void flash_attn(const bf16* __restrict__ Q,
                                                  const bf16* __restrict__ Kb,
                                                  const bf16* __restrict__ Vb,
                                                  bf16* __restrict__ O) {
    __shared__ bf16 Ks[64][72];
    __shared__ bf16 Vt[64][72];   // transposed: Vt[d][n]
    __shared__ bf16 Ps[64][72];
    const int qb = blockIdx.x, h = blockIdx.y;
    const int kvh = h >> 2;
    const int tid = threadIdx.x;
    const int wave = tid >> 6, lane = tid & 63;
    const int quad = lane >> 4, l16 = lane & 15;

    const int qrow = qb * 64 + wave * 16 + l16;
    v8bf qf0 = *(const v8bf*)&Q[(size_t)qrow * DMODEL + h * DH + quad * 8];
    v8bf qf1 = *(const v8bf*)&Q[(size_t)qrow * DMODEL + h * DH + 32 + quad * 8];

    f32x4 oacc[4];
#pragma unroll
    for (int d = 0; d < 4; d++) oacc[d] = (f32x4){0.f, 0.f, 0.f, 0.f};
    float m_i[4], l_i[4];
#pragma unroll
    for (int r = 0; r < 4; r++) { m_i[r] = NEG_BIG; l_i[r] = 0.f; }

    const int r0 = tid >> 3;
    const int cb = (tid & 7) * 8;
    const float scl = 0.125f;     // 1/sqrt(64)

    for (int kb = 0; kb <= qb; kb++) {
        *(v8bf*)&Ks[r0][cb]      = *(const v8bf*)&Kb[(size_t)(kb * 64 + r0) * DKV + kvh * DH + cb];
        *(v8bf*)&Ks[r0 + 32][cb] = *(const v8bf*)&Kb[(size_t)(kb * 64 + r0 + 32) * DKV + kvh * DH + cb];
        {
            v8bf v0 = *(const v8bf*)&Vb[(size_t)(kb * 64 + r0) * DKV + kvh * DH + cb];
            v8bf v1 = *(const v8bf*)&Vb[(size_t)(kb * 64 + r0 + 32) * DKV + kvh * DH + cb];
#pragma unroll
            for (int j = 0; j < 8; j++) {
                Vt[cb + j][r0]      = v0[j];
                Vt[cb + j][r0 + 32] = v1[j];
            }
        }
        __syncthreads();

        f32x4 s[4];
#pragma unroll
        for (int n = 0; n < 4; n++) {
            s[n] = (f32x4){0.f, 0.f, 0.f, 0.f};
            s[n] = __builtin_amdgcn_mfma_f32_16x16x32_bf16(
                qf0, *(v8bf*)&Ks[n * 16 + l16][quad * 8], s[n], 0, 0, 0);
            s[n] = __builtin_amdgcn_mfma_f32_16x16x32_bf16(
                qf1, *(v8bf*)&Ks[n * 16 + l16][32 + quad * 8], s[n], 0, 0, 0);
        }

        const int rowg = qb * 64 + wave * 16 + quad * 4;
        if (kb == qb) {
#pragma unroll
            for (int n = 0; n < 4; n++) {
                int colg = kb * 64 + n * 16 + l16;
#pragma unroll
                for (int r = 0; r < 4; r++)
                    s[n][r] = (colg <= rowg + r) ? s[n][r] * scl : NEG_BIG;
            }
        } else {
#pragma unroll
            for (int n = 0; n < 4; n++)
#pragma unroll
                for (int r = 0; r < 4; r++) s[n][r] *= scl;
        }

        float mx[4];
#pragma unroll
        for (int r = 0; r < 4; r++)
            mx[r] = fmaxf(fmaxf(s[0][r], s[1][r]), fmaxf(s[2][r], s[3][r]));
#pragma unroll
        for (int off = 1; off < 16; off <<= 1)
#pragma unroll
            for (int r = 0; r < 4; r++) mx[r] = fmaxf(mx[r], __shfl_xor(mx[r], off));

        float alpha[4], mnew[4];
#pragma unroll
        for (int r = 0; r < 4; r++) {
            mnew[r]  = fmaxf(m_i[r], mx[r]);
            alpha[r] = __expf(m_i[r] - mnew[r]);
        }

        float rs[4] = {0.f, 0.f, 0.f, 0.f};
#pragma unroll
        for (int n = 0; n < 4; n++)
#pragma unroll
            for (int r = 0; r < 4; r++) {
                float p = __expf(s[n][r] - mnew[r]);
                rs[r] += p;
                Ps[wave * 16 + quad * 4 + r][n * 16 + l16] = (bf16)p;
            }
#pragma unroll
        for (int off = 1; off < 16; off <<= 1)
#pragma unroll
            for (int r = 0; r < 4; r++) rs[r] += __shfl_xor(rs[r], off);
#pragma unroll
        for (int r = 0; r < 4; r++) {
            l_i[r] = l_i[r] * alpha[r] + rs[r];
            m_i[r] = mnew[r];
        }
#pragma unroll
        for (int d = 0; d < 4; d++)
#pragma unroll
            for (int r = 0; r < 4; r++) oacc[d][r] *= alpha[r];

#pragma unroll
        for (int d = 0; d < 4; d++) {
            oacc[d] = __builtin_amdgcn_mfma_f32_16x16x32_bf16(
                *(v8bf*)&Ps[wave * 16 + l16][quad * 8],
                *(v8bf*)&Vt[d * 16 + l16][quad * 8], oacc[d], 0, 0, 0);
            oacc[d] = __builtin_amdgcn_mfma_f32_16x16x32_bf16(
                *(v8bf*)&Ps[wave * 16 + l16][32 + quad * 8],
                *(v8bf*)&Vt[d * 16 + l16][32 + quad * 8], oacc[d], 0, 0, 0);
        }
        __syncthreads();
    }

#pragma unroll
    for (int d = 0; d < 4; d++)
#pragma unroll
        for (int r = 0; r < 4; r++) {
            int row = qb * 64 + wave * 16 + quad * 4 + r;
            int col = h * DH + d * 16 + l16;
            O[(size_t)row * DMODEL + col] = (bf16)(oacc[d][r] / l_i[r]);
        }
}

// ---------------------------------------------------------------------------
extern "C" void kernel_launch(void* const* d_in, const int* in_sizes, int n_in,
                              void* d_out, int out_size, void* d_ws, size_t ws_size,
                              hipStream_t stream) {
    const void* x  = d_in[0];   // f32 (L, D)
    const void* Wq = d_in[1];   // f32 (D, D)
    const void* Wk = d_in[2];   // f32 (DKV, D)
    const void* Wv = d_in[3];   // f32 (DKV, D)
    const void* Wo = d_in[4];   // f32 (D, D)
    const int*  tp = (const int*)d_in[5];
    float* out = (float*)d_out; // f32 (L, D) — reference output dtype is float32

    bf16* Qb   = (bf16*)d_ws;
    bf16* Kbuf = Qb + (size_t)L_SEQ * DMODEL;
    bf16* Vbuf = Kbuf + (size_t)L_SEQ * DKV;
    bf16* Attn = Vbuf + (size_t)L_SEQ * DKV;

    dim3 blk(256);
    // Q = x @ Wq^T  (4096 x 1024)
    gemm_nt<true, true, bf16><<<dim3(16, 64), blk, 0, stream>>>(x, Wq, Qb, DMODEL, DMODEL);
    // K = x @ Wk^T  (4096 x 256)
    gemm_nt<true, true, bf16><<<dim3(4, 64), blk, 0, stream>>>(x, Wk, Kbuf, DKV, DMODEL);
    // V = x @ Wv^T  (4096 x 256)
    gemm_nt<true, true, bf16><<<dim3(4, 64), blk, 0, stream>>>(x, Wv, Vbuf, DKV, DMODEL);
    // RoPE on Q and K
    rope_kernel<<<(L_SEQ * 512 + 255) / 256, blk, 0, stream>>>(Qb, tp, L_SEQ, 512);
    rope_kernel<<<(L_SEQ * 128 + 255) / 256, blk, 0, stream>>>(Kbuf, tp, L_SEQ, 128);
    // attention
    flash_attn<<<dim3(64, NHEADS), blk, 0, stream>>>(Qb, Kbuf, Vbuf, Attn);
    // out = Attn @ Wo^T  -> float32
    gemm_nt<false, true, float><<<dim3(16, 64), blk, 0, stream>>>(Attn, Wo, out, DMODEL, DMODEL);
}

// Round 5
// 362.333 us; speedup vs baseline: 1.3907x; 1.3907x over previous
//
#include <hip/hip_runtime.h>
#include <hip/hip_bf16.h>
#include <math.h>

typedef __bf16 bf16;
typedef __bf16 v8bf __attribute__((ext_vector_type(8)));
typedef float f32x4 __attribute__((ext_vector_type(4)));

#define L_SEQ 4096
#define DMODEL 1024
#define NHEADS 16
#define NKV 4
#define DH 64
#define DKV 256   // NKV * DH
#define NEG_BIG (-1e30f)

// Load 8 contiguous elements (element index idx) as bf16x8; F32 = source dtype.
template <bool F32>
__device__ inline v8bf ld8(const void* __restrict__ p, size_t idx) {
    if (F32) {
        const float* f = (const float*)p + idx;
        f32x4 a = *(const f32x4*)f;
        f32x4 c = *(const f32x4*)(f + 4);
        v8bf r;
#pragma unroll
        for (int j = 0; j < 4; j++) { r[j] = (bf16)a[j]; r[j + 4] = (bf16)c[j]; }
        return r;
    }
    return *(const v8bf*)((const bf16*)p + idx);
}

// ---------------------------------------------------------------------------
// NT GEMM: C[M,N] = A[M,K] * B[N,K]^T   (bf16 MFMA, fp32 accum)
// 64x64 tile, BK=64, 4 waves. (Known-good from round 4.)
// ---------------------------------------------------------------------------
template <bool AF32, bool BF32, typename OutT>
__global__ __launch_bounds__(256) void gemm_nt(const void* __restrict__ A,
                                               const void* __restrict__ B,
                                               OutT* __restrict__ C,
                                               int N, int K) {
    __shared__ bf16 As[64][72];
    __shared__ bf16 Bs[64][72];
    const int tid  = threadIdx.x;
    const int wave = tid >> 6;
    const int lane = tid & 63;
    const int quad = lane >> 4;
    const int l16  = lane & 15;
    const int bm = blockIdx.y * 64;
    const int bn = blockIdx.x * 64;

    f32x4 acc[4];
#pragma unroll
    for (int n = 0; n < 4; n++) acc[n] = (f32x4){0.f, 0.f, 0.f, 0.f};

    const int r0 = tid >> 3;
    const int cb = (tid & 7) * 8;

    for (int kt = 0; kt < K; kt += 64) {
        *(v8bf*)&As[r0][cb]      = ld8<AF32>(A, (size_t)(bm + r0) * K + kt + cb);
        *(v8bf*)&As[r0 + 32][cb] = ld8<AF32>(A, (size_t)(bm + r0 + 32) * K + kt + cb);
        *(v8bf*)&Bs[r0][cb]      = ld8<BF32>(B, (size_t)(bn + r0) * K + kt + cb);
        *(v8bf*)&Bs[r0 + 32][cb] = ld8<BF32>(B, (size_t)(bn + r0 + 32) * K + kt + cb);
        __syncthreads();
#pragma unroll
        for (int ks = 0; ks < 64; ks += 32) {
            v8bf a = *(v8bf*)&As[wave * 16 + l16][ks + quad * 8];
#pragma unroll
            for (int n = 0; n < 4; n++) {
                v8bf b = *(v8bf*)&Bs[n * 16 + l16][ks + quad * 8];
                acc[n] = __builtin_amdgcn_mfma_f32_16x16x32_bf16(a, b, acc[n], 0, 0, 0);
            }
        }
        __syncthreads();
    }
#pragma unroll
    for (int n = 0; n < 4; n++)
#pragma unroll
        for (int r = 0; r < 4; r++) {
            int row = bm + wave * 16 + quad * 4 + r;
            int col = bn + n * 16 + l16;
            C[(size_t)row * N + col] = (OutT)acc[n][r];
        }
}

// ---------------------------------------------------------------------------
// Interleaved RoPE in place on bf16 buffer.
// ---------------------------------------------------------------------------
__global__ void rope_kernel(bf16* __restrict__ X, const int* __restrict__ pos,
                            int rows, int pairs_per_row) {
    int idx = blockIdx.x * blockDim.x + threadIdx.x;
    if (idx >= rows * pairs_per_row) return;
    int row = idx / pairs_per_row;
    int pc  = idx - row * pairs_per_row;
    int i   = pc & 31;
    float freq = expf(-(float)(2 * i) * (9.210340371976184f / 64.0f)); // ln(10000)
    float ang  = (float)pos[row] * freq;
    float c = cosf(ang);
    float s = sinf(ang);
    size_t base = (size_t)row * (pairs_per_row * 2) + 2 * pc;
    float e = (float)X[base];
    float o = (float)X[base + 1];
    X[base]     = (bf16)(e * c - o * s);
    X[base + 1] = (bf16)(e * s + o * c);
}

// ---------------------------------------------------------------------------
// Flash attention v2: BQ=128 rows/block, BK=128 keys/step, 4 waves x 32 rows.
// LDS 54 KB: Ks[128][72] + Vt[64][136] + Ps[128][72] (Ps reused per 64-key half).
// V staged transposed with lane=key scatter -> conflict-free b16 writes.
// Block-size pairing: qb = bx or 31-bx by (y>>3)&1 so c and c+256 balance.
// ---------------------------------------------------------------------------
__global__ __launch_bounds__(256, 2) void flash_attn2(const bf16* __restrict__ Q,
                                                      const bf16* __restrict__ Kb,
                                                      const bf16* __restrict__ Vb,
                                                      bf16* __restrict__ O) {
    __shared__ bf16 Ks[128][72];
    __shared__ bf16 Vt[64][136];
    __shared__ bf16 Ps[128][72];
    const int h = blockIdx.y, kvh = h >> 2;
    const int qb = ((blockIdx.y >> 3) & 1) ? blockIdx.x : (gridDim.x - 1 - blockIdx.x);
    const int tid = threadIdx.x;
    const int w = tid >> 6, lane = tid & 63;
    const int quad = lane >> 4, l16 = lane & 15;

    // Q fragments: 2 m-frags (rows w*32+mf*16+l16) x 2 k-frags (dims kf*32+quad*8..)
    v8bf qf[2][2];
#pragma unroll
    for (int mf = 0; mf < 2; mf++)
#pragma unroll
        for (int kf = 0; kf < 2; kf++)
            qf[mf][kf] = *(const v8bf*)&Q[(size_t)(qb * 128 + w * 32 + mf * 16 + l16) * DMODEL
                                          + h * DH + kf * 32 + quad * 8];

    f32x4 oacc[2][4];
#pragma unroll
    for (int mf = 0; mf < 2; mf++)
#pragma unroll
        for (int d = 0; d < 4; d++) oacc[mf][d] = (f32x4){0.f, 0.f, 0.f, 0.f};
    float m_i[2][4], l_i[2][4];
#pragma unroll
    for (int mf = 0; mf < 2; mf++)
#pragma unroll
        for (int r = 0; r < 4; r++) { m_i[mf][r] = NEG_BIG; l_i[mf][r] = 0.f; }

    const int krow = tid >> 1;             // 0..127 (K staging row)
    const int kcb  = (tid & 1) * 32;       // 0 or 32 (K staging col base)
    const float scl = 0.125f;              // 1/sqrt(64)

    for (int kb = 0; kb <= qb; kb++) {
        __syncthreads();   // previous step's LDS reads complete before restage
        // ---- stage K tile [128 keys x 64 dims], natural layout
        {
            const bf16* src = &Kb[(size_t)(kb * 128 + krow) * DKV + kvh * DH + kcb];
#pragma unroll
            for (int u = 0; u < 4; u++)
                *(v8bf*)&Ks[krow][kcb + 8 * u] = *(const v8bf*)&src[8 * u];
        }
        // ---- stage V transposed: lane=key scatter => conflict-free writes
#pragma unroll
        for (int it = 0; it < 4; it++) {
            int task = w * 4 + it;         // 0..15
            int half = task & 1;           // key half (0..1)
            int c    = task >> 1;          // dim chunk (0..7)
            int key  = half * 64 + lane;
            v8bf v = *(const v8bf*)&Vb[(size_t)(kb * 128 + key) * DKV + kvh * DH + c * 8];
#pragma unroll
            for (int j = 0; j < 8; j++) Vt[c * 8 + j][key] = v[j];
        }
        __syncthreads();

        // ---- S = Q K^T : 2 m-frags x 8 n-tiles
        f32x4 s[2][8];
#pragma unroll
        for (int n = 0; n < 8; n++) {
            v8bf b0 = *(v8bf*)&Ks[n * 16 + l16][quad * 8];
            v8bf b1 = *(v8bf*)&Ks[n * 16 + l16][32 + quad * 8];
#pragma unroll
            for (int mf = 0; mf < 2; mf++) {
                s[mf][n] = (f32x4){0.f, 0.f, 0.f, 0.f};
                s[mf][n] = __builtin_amdgcn_mfma_f32_16x16x32_bf16(qf[mf][0], b0, s[mf][n], 0, 0, 0);
                s[mf][n] = __builtin_amdgcn_mfma_f32_16x16x32_bf16(qf[mf][1], b1, s[mf][n], 0, 0, 0);
            }
        }

        // ---- scale + causal mask (only diagonal block needs masking)
        if (kb == qb) {
#pragma unroll
            for (int mf = 0; mf < 2; mf++) {
                int rbase = qb * 128 + w * 32 + mf * 16 + quad * 4;
#pragma unroll
                for (int n = 0; n < 8; n++) {
                    int colg = kb * 128 + n * 16 + l16;
#pragma unroll
                    for (int r = 0; r < 4; r++)
                        s[mf][n][r] = (colg <= rbase + r) ? s[mf][n][r] * scl : NEG_BIG;
                }
            }
        } else {
#pragma unroll
            for (int mf = 0; mf < 2; mf++)
#pragma unroll
                for (int n = 0; n < 8; n++)
#pragma unroll
                    for (int r = 0; r < 4; r++) s[mf][n][r] *= scl;
        }

        // ---- online softmax state update
        float mx[2][4];
#pragma unroll
        for (int mf = 0; mf < 2; mf++)
#pragma unroll
            for (int r = 0; r < 4; r++) {
                float m0 = s[mf][0][r];
#pragma unroll
                for (int n = 1; n < 8; n++) m0 = fmaxf(m0, s[mf][n][r]);
                mx[mf][r] = m0;
            }
#pragma unroll
        for (int off = 1; off < 16; off <<= 1)
#pragma unroll
            for (int mf = 0; mf < 2; mf++)
#pragma unroll
                for (int r = 0; r < 4; r++)
                    mx[mf][r] = fmaxf(mx[mf][r], __shfl_xor(mx[mf][r], off));

        float alpha[2][4], mnew[2][4], rs[2][4];
#pragma unroll
        for (int mf = 0; mf < 2; mf++)
#pragma unroll
            for (int r = 0; r < 4; r++) {
                mnew[mf][r]  = fmaxf(m_i[mf][r], mx[mf][r]);
                alpha[mf][r] = __expf(m_i[mf][r] - mnew[mf][r]);
                rs[mf][r] = 0.f;
            }

        // ---- P = exp(S - mnew), accumulate row sums (all 8 n-tiles)
#pragma unroll
        for (int mf = 0; mf < 2; mf++)
#pragma unroll
            for (int n = 0; n < 8; n++)
#pragma unroll
                for (int r = 0; r < 4; r++) {
                    float p = __expf(s[mf][n][r] - mnew[mf][r]);
                    s[mf][n][r] = p;
                    rs[mf][r] += p;
                }
#pragma unroll
        for (int off = 1; off < 16; off <<= 1)
#pragma unroll
            for (int mf = 0; mf < 2; mf++)
#pragma unroll
                for (int r = 0; r < 4; r++) rs[mf][r] += __shfl_xor(rs[mf][r], off);
#pragma unroll
        for (int mf = 0; mf < 2; mf++)
#pragma unroll
            for (int r = 0; r < 4; r++) {
                l_i[mf][r] = l_i[mf][r] * alpha[mf][r] + rs[mf][r];
                m_i[mf][r] = mnew[mf][r];
            }
#pragma unroll
        for (int mf = 0; mf < 2; mf++)
#pragma unroll
            for (int d = 0; d < 4; d++)
#pragma unroll
                for (int r = 0; r < 4; r++) oacc[mf][d][r] *= alpha[mf][r];

        // ---- PV in two 64-key halves (Ps buffer holds 64 key-cols at a time).
        // Ps rows [w*32, w*32+32) are private to this wave: no barrier needed.
#pragma unroll
        for (int halfk = 0; halfk < 2; halfk++) {
#pragma unroll
            for (int mf = 0; mf < 2; mf++)
#pragma unroll
                for (int n = 0; n < 4; n++)
#pragma unroll
                    for (int r = 0; r < 4; r++)
                        Ps[w * 32 + mf * 16 + quad * 4 + r][n * 16 + l16] =
                            (bf16)s[mf][halfk * 4 + n][r];
#pragma unroll
            for (int kf = 0; kf < 2; kf++) {
                int kk = halfk * 2 + kf;   // global k-frag (0..3) for Vt cols
#pragma unroll
                for (int mf = 0; mf < 2; mf++) {
                    v8bf pa = *(v8bf*)&Ps[w * 32 + mf * 16 + l16][kf * 32 + quad * 8];
#pragma unroll
                    for (int d = 0; d < 4; d++) {
                        v8bf vb = *(v8bf*)&Vt[d * 16 + l16][kk * 32 + quad * 8];
                        oacc[mf][d] = __builtin_amdgcn_mfma_f32_16x16x32_bf16(pa, vb, oacc[mf][d], 0, 0, 0);
                    }
                }
            }
        }
    }

    // ---- normalize + write
#pragma unroll
    for (int mf = 0; mf < 2; mf++)
#pragma unroll
        for (int d = 0; d < 4; d++)
#pragma unroll
            for (int r = 0; r < 4; r++) {
                int row = qb * 128 + w * 32 + mf * 16 + quad * 4 + r;
                int col = h * DH + d * 16 + l16;
                O[(size_t)row * DMODEL + col] = (bf16)(oacc[mf][d][r] / l_i[mf][r]);
            }
}

// ---------------------------------------------------------------------------
extern "C" void kernel_launch(void* const* d_in, const int* in_sizes, int n_in,
                              void* d_out, int out_size, void* d_ws, size_t ws_size,
                              hipStream_t stream) {
    const void* x  = d_in[0];   // f32 (L, D)
    const void* Wq = d_in[1];   // f32 (D, D)
    const void* Wk = d_in[2];   // f32 (DKV, D)
    const void* Wv = d_in[3];   // f32 (DKV, D)
    const void* Wo = d_in[4];   // f32 (D, D)
    const int*  tp = (const int*)d_in[5];
    float* out = (float*)d_out; // f32 (L, D)

    bf16* Qb   = (bf16*)d_ws;
    bf16* Kbuf = Qb + (size_t)L_SEQ * DMODEL;
    bf16* Vbuf = Kbuf + (size_t)L_SEQ * DKV;
    bf16* Attn = Vbuf + (size_t)L_SEQ * DKV;

    dim3 blk(256);
    gemm_nt<true, true, bf16><<<dim3(16, 64), blk, 0, stream>>>(x, Wq, Qb, DMODEL, DMODEL);
    gemm_nt<true, true, bf16><<<dim3(4, 64), blk, 0, stream>>>(x, Wk, Kbuf, DKV, DMODEL);
    gemm_nt<true, true, bf16><<<dim3(4, 64), blk, 0, stream>>>(x, Wv, Vbuf, DKV, DMODEL);
    rope_kernel<<<(L_SEQ * 512 + 255) / 256, blk, 0, stream>>>(Qb, tp, L_SEQ, 512);
    rope_kernel<<<(L_SEQ * 128 + 255) / 256, blk, 0, stream>>>(Kbuf, tp, L_SEQ, 128);
    flash_attn2<<<dim3(L_SEQ / 128, NHEADS), blk, 0, stream>>>(Qb, Kbuf, Vbuf, Attn);
    gemm_nt<false, true, float><<<dim3(16, 64), blk, 0, stream>>>(Attn, Wo, out, DMODEL, DMODEL);
}

// Round 6
// 351.968 us; speedup vs baseline: 1.4316x; 1.0294x over previous
//
#include <hip/hip_runtime.h>
#include <hip/hip_bf16.h>
#include <math.h>

typedef __bf16 bf16;
typedef __bf16 v8bf __attribute__((ext_vector_type(8)));
typedef __bf16 v4bf __attribute__((ext_vector_type(4)));
typedef float f32x4 __attribute__((ext_vector_type(4)));

#define L_SEQ 4096
#define DMODEL 1024
#define NHEADS 16
#define DH 64
#define DKV2 512         // concat KV row width (K cols 0..255, V cols 256..511)
#define NEG_BIG (-1e30f)
#define LN1E4_64 0.14391156f   // ln(10000)/64

// ---------------------------------------------------------------------------
// One-shot f32 -> bf16 conversion of all inputs.
// Segments (element offsets, all multiples of 4):
//   [0,4194304) x -> xb ; [..,5242880) Wq -> wqb ; [..,5505024) Wk -> wkvb[0:]
//   [..,5767168) Wv -> wkvb[262144:] ; [..,6815744) Wo -> wob
// ---------------------------------------------------------------------------
__global__ void convert_all(const float* __restrict__ x, const float* __restrict__ wq,
                            const float* __restrict__ wk, const float* __restrict__ wv,
                            const float* __restrict__ wo,
                            bf16* __restrict__ xb, bf16* __restrict__ wqb,
                            bf16* __restrict__ wkvb, bf16* __restrict__ wob) {
    int i = (blockIdx.x * 256 + threadIdx.x) * 4;
    const float* src;
    bf16* dst;
    if (i < 4194304)      { src = x  + i;             dst = xb   + i; }
    else if (i < 5242880) { src = wq + (i - 4194304); dst = wqb  + (i - 4194304); }
    else if (i < 5505024) { src = wk + (i - 5242880); dst = wkvb + (i - 5242880); }
    else if (i < 5767168) { src = wv + (i - 5505024); dst = wkvb + 262144 + (i - 5505024); }
    else                  { src = wo + (i - 5767168); dst = wob  + (i - 5767168); }
    f32x4 v = *(const f32x4*)src;
    v4bf r;
#pragma unroll
    for (int j = 0; j < 4; j++) r[j] = (bf16)v[j];
    *(v4bf*)dst = r;
}

// ---------------------------------------------------------------------------
// 128x128-tile NT GEMM: C[M,N] = A[M,K] * B[N,K]^T, bf16 in, fp32 accum.
// 4 waves in 2x2; each wave owns a 64x64 sub-tile (4x4 fragments).
// ROPE: 0=none, 1=apply to all cols, 2=apply iff col<256 (K region of KV).
// RoPE fused in epilogue: pair = adjacent cols = adjacent lanes (shfl_xor 1).
// ---------------------------------------------------------------------------
template <int ROPE, typename OutT>
__global__ __launch_bounds__(256) void gemm128(const bf16* __restrict__ A,
                                               const bf16* __restrict__ B,
                                               OutT* __restrict__ C,
                                               int N, int K,
                                               const int* __restrict__ tp) {
    __shared__ bf16 As[128][72];
    __shared__ bf16 Bs[128][72];
    const int tid = threadIdx.x;
    const int w = tid >> 6, lane = tid & 63;
    const int quad = lane >> 4, l16 = lane & 15;
    const int wm = (w & 1) * 64, wn = (w >> 1) * 64;
    const int bm = blockIdx.y * 128, bn = blockIdx.x * 128;

    f32x4 acc[4][4];
#pragma unroll
    for (int mf = 0; mf < 4; mf++)
#pragma unroll
        for (int nf = 0; nf < 4; nf++) acc[mf][nf] = (f32x4){0.f, 0.f, 0.f, 0.f};

    const int sr = tid >> 3;        // 0..31
    const int scb = (tid & 7) * 8;  // 0..56

    for (int kt = 0; kt < K; kt += 64) {
#pragma unroll
        for (int u = 0; u < 4; u++) {
            *(v8bf*)&As[u * 32 + sr][scb] = *(const v8bf*)&A[(size_t)(bm + u * 32 + sr) * K + kt + scb];
            *(v8bf*)&Bs[u * 32 + sr][scb] = *(const v8bf*)&B[(size_t)(bn + u * 32 + sr) * K + kt + scb];
        }
        __syncthreads();
#pragma unroll
        for (int kf = 0; kf < 2; kf++) {
            v8bf a[4], b[4];
#pragma unroll
            for (int mf = 0; mf < 4; mf++) a[mf] = *(v8bf*)&As[wm + mf * 16 + l16][kf * 32 + quad * 8];
#pragma unroll
            for (int nf = 0; nf < 4; nf++) b[nf] = *(v8bf*)&Bs[wn + nf * 16 + l16][kf * 32 + quad * 8];
#pragma unroll
            for (int mf = 0; mf < 4; mf++)
#pragma unroll
                for (int nf = 0; nf < 4; nf++)
                    acc[mf][nf] = __builtin_amdgcn_mfma_f32_16x16x32_bf16(a[mf], b[nf], acc[mf][nf], 0, 0, 0);
        }
        __syncthreads();
    }

    // ---- epilogue (+fused RoPE) ----
    const bool doRope = (ROPE == 1) || (ROPE == 2 && (bn + wn) < 256);   // block/wave-uniform
#pragma unroll
    for (int mf = 0; mf < 4; mf++) {
        int pos_[4];
        if (doRope) {
#pragma unroll
            for (int r = 0; r < 4; r++) pos_[r] = tp[bm + wm + mf * 16 + quad * 4 + r];
        }
#pragma unroll
        for (int nf = 0; nf < 4; nf++) {
            const int col = bn + wn + nf * 16 + l16;
            float fr = 0.f;
            if (doRope) {
                int i2 = ((nf * 16 + l16) >> 1) * 2;   // 2*i within 64-wide head
                fr = __expf(-(float)i2 * LN1E4_64);
            }
#pragma unroll
            for (int r = 0; r < 4; r++) {
                float v = acc[mf][nf][r];
                float res = v;
                if (doRope) {
                    float ang = (float)pos_[r] * fr;
                    float sn, cs;
                    __sincosf(ang, &sn, &cs);
                    float p = __shfl_xor(v, 1);
                    res = (l16 & 1) ? (p * sn + v * cs) : (v * cs - p * sn);
                }
                int row = bm + wm + mf * 16 + quad * 4 + r;
                C[(size_t)row * N + col] = (OutT)res;
            }
        }
    }
}

// ---------------------------------------------------------------------------
// Flash attention v3: BQ=64 rows/block, BK=128 keys/step, 4 waves x 16 rows.
// Grid (64, 16) = 1024 blocks -> 4 blocks/CU. LDS 35 KB: P-tile aliases K-tile
// (extra barrier after S drains all K reads before P overwrites it).
// KV combined buffer: row stride 512, K at col kvh*64, V at col 256+kvh*64.
// ---------------------------------------------------------------------------
__global__ __launch_bounds__(256, 4) void flash_attn3(const bf16* __restrict__ Q,
                                                      const bf16* __restrict__ KV,
                                                      bf16* __restrict__ O) {
    __shared__ bf16 KsPs[128][72];   // K tile, diagonally reused as P tile
    __shared__ bf16 Vt[64][136];     // V transposed [dim][key]
    const int h = blockIdx.y, kvh = h >> 2;
    const int qb = (h & 1) ? (int)blockIdx.x : (int)(gridDim.x - 1 - blockIdx.x);
    const int tid = threadIdx.x;
    const int w = tid >> 6, lane = tid & 63;
    const int quad = lane >> 4, l16 = lane & 15;

    const size_t qrow = (size_t)(qb * 64 + w * 16 + l16);
    v8bf qf0 = *(const v8bf*)&Q[qrow * DMODEL + h * DH + quad * 8];
    v8bf qf1 = *(const v8bf*)&Q[qrow * DMODEL + h * DH + 32 + quad * 8];

    f32x4 oacc[4];
#pragma unroll
    for (int d = 0; d < 4; d++) oacc[d] = (f32x4){0.f, 0.f, 0.f, 0.f};
    float m_i[4], l_i[4];
#pragma unroll
    for (int r = 0; r < 4; r++) { m_i[r] = NEG_BIG; l_i[r] = 0.f; }

    const int krow = tid >> 1;        // 0..127
    const int kcb  = (tid & 1) * 32;  // 0 / 32
    const float scl = 0.125f;         // 1/sqrt(64)
    const int kbmax = qb >> 1;

    for (int kb = 0; kb <= kbmax; kb++) {
        __syncthreads();   // prior PV reads (KsPs, Vt) complete before restage
        {
            const bf16* src = &KV[(size_t)(kb * 128 + krow) * DKV2 + kvh * DH + kcb];
#pragma unroll
            for (int u = 0; u < 4; u++)
                *(v8bf*)&KsPs[krow][kcb + 8 * u] = *(const v8bf*)&src[8 * u];
        }
#pragma unroll
        for (int it = 0; it < 4; it++) {
            int task = w * 4 + it;     // 0..15
            int half = task & 1;
            int c    = task >> 1;      // dim chunk 0..7
            int key  = half * 64 + lane;
            v8bf v = *(const v8bf*)&KV[(size_t)(kb * 128 + key) * DKV2 + 256 + kvh * DH + c * 8];
#pragma unroll
            for (int j = 0; j < 8; j++) Vt[c * 8 + j][key] = v[j];
        }
        __syncthreads();

        // ---- S = Q K^T : 16 rows x 128 keys per wave
        f32x4 s[8];
#pragma unroll
        for (int n = 0; n < 8; n++) {
            v8bf b0 = *(v8bf*)&KsPs[n * 16 + l16][quad * 8];
            v8bf b1 = *(v8bf*)&KsPs[n * 16 + l16][32 + quad * 8];
            s[n] = (f32x4){0.f, 0.f, 0.f, 0.f};
            s[n] = __builtin_amdgcn_mfma_f32_16x16x32_bf16(qf0, b0, s[n], 0, 0, 0);
            s[n] = __builtin_amdgcn_mfma_f32_16x16x32_bf16(qf1, b1, s[n], 0, 0, 0);
        }

        // ---- scale + causal mask (diagonal step only)
        if (kb == kbmax) {
            const int rbase = qb * 64 + w * 16 + quad * 4;
#pragma unroll
            for (int n = 0; n < 8; n++) {
                int colg = kb * 128 + n * 16 + l16;
#pragma unroll
                for (int r = 0; r < 4; r++)
                    s[n][r] = (colg <= rbase + r) ? s[n][r] * scl : NEG_BIG;
            }
        } else {
#pragma unroll
            for (int n = 0; n < 8; n++)
#pragma unroll
                for (int r = 0; r < 4; r++) s[n][r] *= scl;
        }

        // ---- online softmax
        float mx[4];
#pragma unroll
        for (int r = 0; r < 4; r++) {
            float m0 = s[0][r];
#pragma unroll
            for (int n = 1; n < 8; n++) m0 = fmaxf(m0, s[n][r]);
            mx[r] = m0;
        }
#pragma unroll
        for (int off = 1; off < 16; off <<= 1)
#pragma unroll
            for (int r = 0; r < 4; r++) mx[r] = fmaxf(mx[r], __shfl_xor(mx[r], off));

        float alpha[4], mnew[4], rs[4];
#pragma unroll
        for (int r = 0; r < 4; r++) {
            mnew[r]  = fmaxf(m_i[r], mx[r]);
            alpha[r] = __expf(m_i[r] - mnew[r]);
            rs[r] = 0.f;
        }
#pragma unroll
        for (int n = 0; n < 8; n++)
#pragma unroll
            for (int r = 0; r < 4; r++) {
                float p = __expf(s[n][r] - mnew[r]);
                s[n][r] = p;
                rs[r] += p;
            }
#pragma unroll
        for (int off = 1; off < 16; off <<= 1)
#pragma unroll
            for (int r = 0; r < 4; r++) rs[r] += __shfl_xor(rs[r], off);
#pragma unroll
        for (int r = 0; r < 4; r++) {
            l_i[r] = l_i[r] * alpha[r] + rs[r];
            m_i[r] = mnew[r];
        }
#pragma unroll
        for (int d = 0; d < 4; d++)
#pragma unroll
            for (int r = 0; r < 4; r++) oacc[d][r] *= alpha[r];

        __syncthreads();   // ALL waves' K reads drained -> safe to overwrite with P

        // ---- PV in two 64-key halves; P rows [w*16, w*16+16) are wave-private
#pragma unroll
        for (int half = 0; half < 2; half++) {
#pragma unroll
            for (int n = 0; n < 4; n++)
#pragma unroll
                for (int r = 0; r < 4; r++)
                    KsPs[w * 16 + quad * 4 + r][n * 16 + l16] = (bf16)s[half * 4 + n][r];
#pragma unroll
            for (int kf = 0; kf < 2; kf++) {
                v8bf pa = *(v8bf*)&KsPs[w * 16 + l16][kf * 32 + quad * 8];
#pragma unroll
                for (int d = 0; d < 4; d++) {
                    v8bf vb = *(v8bf*)&Vt[d * 16 + l16][half * 64 + kf * 32 + quad * 8];
                    oacc[d] = __builtin_amdgcn_mfma_f32_16x16x32_bf16(pa, vb, oacc[d], 0, 0, 0);
                }
            }
        }
    }

    // ---- normalize + write
#pragma unroll
    for (int d = 0; d < 4; d++)
#pragma unroll
        for (int r = 0; r < 4; r++) {
            int row = qb * 64 + w * 16 + quad * 4 + r;
            int col = h * DH + d * 16 + l16;
            O[(size_t)row * DMODEL + col] = (bf16)(oacc[d][r] / l_i[r]);
        }
}

// ---------------------------------------------------------------------------
extern "C" void kernel_launch(void* const* d_in, const int* in_sizes, int n_in,
                              void* d_out, int out_size, void* d_ws, size_t ws_size,
                              hipStream_t stream) {
    const float* x  = (const float*)d_in[0];
    const float* Wq = (const float*)d_in[1];
    const float* Wk = (const float*)d_in[2];
    const float* Wv = (const float*)d_in[3];
    const float* Wo = (const float*)d_in[4];
    const int*   tp = (const int*)d_in[5];
    float* out = (float*)d_out;

    bf16* xb   = (bf16*)d_ws;                 // 4194304 elems; later reused as Attn
    bf16* wqb  = xb   + 4194304;              // 1048576
    bf16* wkvb = wqb  + 1048576;              // 524288 ([Wk;Wv] as [512,1024])
    bf16* wob  = wkvb + 524288;               // 1048576
    bf16* Qb   = wob  + 1048576;              // 4194304
    bf16* KVb  = Qb   + 4194304;              // 2097152 ([4096,512])
    bf16* Attn = xb;  // alias: x last read by KV projection, before flash writes

    convert_all<<<6656, 256, 0, stream>>>(x, Wq, Wk, Wv, Wo, xb, wqb, wkvb, wob);
    // Q = x @ Wq^T with fused RoPE   (4096 x 1024)
    gemm128<1, bf16><<<dim3(8, 32), 256, 0, stream>>>(xb, wqb, Qb, DMODEL, DMODEL, tp);
    // KV = x @ [Wk;Wv]^T, RoPE on K half only   (4096 x 512)
    gemm128<2, bf16><<<dim3(4, 32), 256, 0, stream>>>(xb, wkvb, KVb, DKV2, DMODEL, tp);
    // attention
    flash_attn3<<<dim3(64, NHEADS), 256, 0, stream>>>(Qb, KVb, Attn);
    // out = Attn @ Wo^T -> float32
    gemm128<0, float><<<dim3(8, 32), 256, 0, stream>>>(Attn, wob, out, DMODEL, DMODEL, nullptr);
}

// Round 7
// 271.174 us; speedup vs baseline: 1.8582x; 1.2979x over previous
//
#include <hip/hip_runtime.h>
#include <hip/hip_bf16.h>
#include <math.h>

typedef __bf16 bf16;
typedef __bf16 v8bf __attribute__((ext_vector_type(8)));
typedef __bf16 v4bf __attribute__((ext_vector_type(4)));
typedef float f32x4 __attribute__((ext_vector_type(4)));

#define L_SEQ 4096
#define DMODEL 1024
#define NHEADS 16
#define DH 64
#define NEG_BIG (-1e30f)
#define LN1E4_64 0.14391156f   // ln(10000)/64

// ---------------------------------------------------------------------------
// One-shot f32 -> bf16 conversion of all inputs.
// ---------------------------------------------------------------------------
__global__ void convert_all(const float* __restrict__ x, const float* __restrict__ wq,
                            const float* __restrict__ wk, const float* __restrict__ wv,
                            const float* __restrict__ wo,
                            bf16* __restrict__ xb, bf16* __restrict__ wqb,
                            bf16* __restrict__ wkvb, bf16* __restrict__ wob) {
    int i = (blockIdx.x * 256 + threadIdx.x) * 4;
    const float* src;
    bf16* dst;
    if (i < 4194304)      { src = x  + i;             dst = xb   + i; }
    else if (i < 5242880) { src = wq + (i - 4194304); dst = wqb  + (i - 4194304); }
    else if (i < 5505024) { src = wk + (i - 5242880); dst = wkvb + (i - 5242880); }
    else if (i < 5767168) { src = wv + (i - 5505024); dst = wkvb + 262144 + (i - 5505024); }
    else                  { src = wo + (i - 5767168); dst = wob  + (i - 5767168); }
    f32x4 v = *(const f32x4*)src;
    v4bf r;
#pragma unroll
    for (int j = 0; j < 4; j++) r[j] = (bf16)v[j];
    *(v4bf*)dst = r;
}

// ---------------------------------------------------------------------------
// 128x128-tile NT GEMM: C[M,N] = A[M,K] * B[N,K]^T, bf16 in, fp32 accum.
// ROPE: 0=none (OutT out), 1=fused interleaved RoPE on all cols (bf16 out).
// ---------------------------------------------------------------------------
template <int ROPE, typename OutT>
__global__ __launch_bounds__(256) void gemm128(const bf16* __restrict__ A,
                                               const bf16* __restrict__ B,
                                               OutT* __restrict__ C,
                                               int N, int K,
                                               const int* __restrict__ tp) {
    __shared__ bf16 As[128][72];
    __shared__ bf16 Bs[128][72];
    const int tid = threadIdx.x;
    const int w = tid >> 6, lane = tid & 63;
    const int quad = lane >> 4, l16 = lane & 15;
    const int wm = (w & 1) * 64, wn = (w >> 1) * 64;
    const int bm = blockIdx.y * 128, bn = blockIdx.x * 128;

    f32x4 acc[4][4];
#pragma unroll
    for (int mf = 0; mf < 4; mf++)
#pragma unroll
        for (int nf = 0; nf < 4; nf++) acc[mf][nf] = (f32x4){0.f, 0.f, 0.f, 0.f};

    const int sr = tid >> 3;
    const int scb = (tid & 7) * 8;

    for (int kt = 0; kt < K; kt += 64) {
#pragma unroll
        for (int u = 0; u < 4; u++) {
            *(v8bf*)&As[u * 32 + sr][scb] = *(const v8bf*)&A[(size_t)(bm + u * 32 + sr) * K + kt + scb];
            *(v8bf*)&Bs[u * 32 + sr][scb] = *(const v8bf*)&B[(size_t)(bn + u * 32 + sr) * K + kt + scb];
        }
        __syncthreads();
#pragma unroll
        for (int kf = 0; kf < 2; kf++) {
            v8bf a[4], b[4];
#pragma unroll
            for (int mf = 0; mf < 4; mf++) a[mf] = *(v8bf*)&As[wm + mf * 16 + l16][kf * 32 + quad * 8];
#pragma unroll
            for (int nf = 0; nf < 4; nf++) b[nf] = *(v8bf*)&Bs[wn + nf * 16 + l16][kf * 32 + quad * 8];
#pragma unroll
            for (int mf = 0; mf < 4; mf++)
#pragma unroll
                for (int nf = 0; nf < 4; nf++)
                    acc[mf][nf] = __builtin_amdgcn_mfma_f32_16x16x32_bf16(a[mf], b[nf], acc[mf][nf], 0, 0, 0);
        }
        __syncthreads();
    }

#pragma unroll
    for (int mf = 0; mf < 4; mf++) {
        int pos_[4];
        if (ROPE == 1) {
#pragma unroll
            for (int r = 0; r < 4; r++) pos_[r] = tp[bm + wm + mf * 16 + quad * 4 + r];
        }
#pragma unroll
        for (int nf = 0; nf < 4; nf++) {
            const int col = bn + wn + nf * 16 + l16;
            float fr = 0.f;
            if (ROPE == 1) {
                int i2 = ((nf * 16 + l16) >> 1) * 2;   // 2*i within 64-wide head
                fr = __expf(-(float)i2 * LN1E4_64);
            }
#pragma unroll
            for (int r = 0; r < 4; r++) {
                float v = acc[mf][nf][r];
                float res = v;
                if (ROPE == 1) {
                    float ang = (float)pos_[r] * fr;
                    float sn, cs;
                    __sincosf(ang, &sn, &cs);
                    float p = __shfl_xor(v, 1);
                    res = (l16 & 1) ? (p * sn + v * cs) : (v * cs - p * sn);
                }
                int row = bm + wm + mf * 16 + quad * 4 + r;
                C[(size_t)row * N + col] = (OutT)res;
            }
        }
    }
}

// ---------------------------------------------------------------------------
// KV projection: C[4096][512] = x @ [Wk;Wv]^T.
// Cols 0..255 (K): RoPE fused, stored natural to Kb[4096][256].
// Cols 256..511 (V): stored TRANSPOSED to Vtg[256][4096] (packed v4bf rows).
// ---------------------------------------------------------------------------
__global__ __launch_bounds__(256) void gemm_kv(const bf16* __restrict__ A,
                                               const bf16* __restrict__ B,
                                               bf16* __restrict__ Kb,
                                               bf16* __restrict__ Vtg,
                                               const int* __restrict__ tp) {
    __shared__ bf16 As[128][72];
    __shared__ bf16 Bs[128][72];
    const int N = 512, K = 1024;
    const int tid = threadIdx.x;
    const int w = tid >> 6, lane = tid & 63;
    const int quad = lane >> 4, l16 = lane & 15;
    const int wm = (w & 1) * 64, wn = (w >> 1) * 64;
    const int bm = blockIdx.y * 128, bn = blockIdx.x * 128;

    f32x4 acc[4][4];
#pragma unroll
    for (int mf = 0; mf < 4; mf++)
#pragma unroll
        for (int nf = 0; nf < 4; nf++) acc[mf][nf] = (f32x4){0.f, 0.f, 0.f, 0.f};

    const int sr = tid >> 3;
    const int scb = (tid & 7) * 8;

    for (int kt = 0; kt < K; kt += 64) {
#pragma unroll
        for (int u = 0; u < 4; u++) {
            *(v8bf*)&As[u * 32 + sr][scb] = *(const v8bf*)&A[(size_t)(bm + u * 32 + sr) * K + kt + scb];
            *(v8bf*)&Bs[u * 32 + sr][scb] = *(const v8bf*)&B[(size_t)(bn + u * 32 + sr) * K + kt + scb];
        }
        __syncthreads();
#pragma unroll
        for (int kf = 0; kf < 2; kf++) {
            v8bf a[4], b[4];
#pragma unroll
            for (int mf = 0; mf < 4; mf++) a[mf] = *(v8bf*)&As[wm + mf * 16 + l16][kf * 32 + quad * 8];
#pragma unroll
            for (int nf = 0; nf < 4; nf++) b[nf] = *(v8bf*)&Bs[wn + nf * 16 + l16][kf * 32 + quad * 8];
#pragma unroll
            for (int mf = 0; mf < 4; mf++)
#pragma unroll
                for (int nf = 0; nf < 4; nf++)
                    acc[mf][nf] = __builtin_amdgcn_mfma_f32_16x16x32_bf16(a[mf], b[nf], acc[mf][nf], 0, 0, 0);
        }
        __syncthreads();
    }

    if (bn < 256) {   // ---- K region: RoPE + natural store ----
#pragma unroll
        for (int mf = 0; mf < 4; mf++) {
            int pos_[4];
#pragma unroll
            for (int r = 0; r < 4; r++) pos_[r] = tp[bm + wm + mf * 16 + quad * 4 + r];
#pragma unroll
            for (int nf = 0; nf < 4; nf++) {
                const int col = bn + wn + nf * 16 + l16;
                int i2 = ((nf * 16 + l16) >> 1) * 2;
                float fr = __expf(-(float)i2 * LN1E4_64);
#pragma unroll
                for (int r = 0; r < 4; r++) {
                    float v = acc[mf][nf][r];
                    float ang = (float)pos_[r] * fr;
                    float sn, cs;
                    __sincosf(ang, &sn, &cs);
                    float p = __shfl_xor(v, 1);
                    float res = (l16 & 1) ? (p * sn + v * cs) : (v * cs - p * sn);
                    int row = bm + wm + mf * 16 + quad * 4 + r;
                    Kb[(size_t)row * 256 + col] = (bf16)res;
                }
            }
        }
    } else {          // ---- V region: transposed store, packed over r ----
#pragma unroll
        for (int mf = 0; mf < 4; mf++)
#pragma unroll
            for (int nf = 0; nf < 4; nf++) {
                v4bf pk;
#pragma unroll
                for (int r = 0; r < 4; r++) pk[r] = (bf16)acc[mf][nf][r];
                int col = bn + wn + nf * 16 + l16 - 256;         // V dim 0..255
                int row = bm + wm + mf * 16 + quad * 4;          // seq pos (mult of 4)
                *(v4bf*)&Vtg[(size_t)col * L_SEQ + row] = pk;
            }
    }
}

// ---------------------------------------------------------------------------
// Flash attention v4: BQ=128, BK=128, 4 waves x 32 rows.
// K from Kb[4096][256] (natural), V from Vtg[256][4096] (pre-transposed) --
// both staged fully coalesced. Register prefetch of next K/V tile overlaps
// global latency with S/softmax/PV compute. 2 barriers/step.
// ---------------------------------------------------------------------------
__global__ __launch_bounds__(256, 2) void flash_attn4(const bf16* __restrict__ Q,
                                                      const bf16* __restrict__ Kb,
                                                      const bf16* __restrict__ Vtg,
                                                      bf16* __restrict__ O) {
    __shared__ bf16 Ks[128][72];
    __shared__ bf16 Vt[64][136];
    __shared__ bf16 Ps[128][72];
    const int h = blockIdx.y, kvh = h >> 2;
    const int qb = ((blockIdx.y >> 3) & 1) ? (int)blockIdx.x : (int)(gridDim.x - 1 - blockIdx.x);
    const int tid = threadIdx.x;
    const int w = tid >> 6, lane = tid & 63;
    const int quad = lane >> 4, l16 = lane & 15;

    // Q fragments: rows w*32+mf*16+l16, dims kf*32+quad*8..
    v8bf qf[2][2];
#pragma unroll
    for (int mf = 0; mf < 2; mf++)
#pragma unroll
        for (int kf = 0; kf < 2; kf++)
            qf[mf][kf] = *(const v8bf*)&Q[(size_t)(qb * 128 + w * 32 + mf * 16 + l16) * DMODEL
                                          + h * DH + kf * 32 + quad * 8];

    f32x4 oacc[2][4];
#pragma unroll
    for (int mf = 0; mf < 2; mf++)
#pragma unroll
        for (int d = 0; d < 4; d++) oacc[mf][d] = (f32x4){0.f, 0.f, 0.f, 0.f};
    float m_i[2][4], l_i[2][4];
#pragma unroll
    for (int mf = 0; mf < 2; mf++)
#pragma unroll
        for (int r = 0; r < 4; r++) { m_i[mf][r] = NEG_BIG; l_i[mf][r] = 0.f; }

    // staging maps (both coalesced)
    const int krow = tid >> 1, kcb = (tid & 1) * 32;    // K: [128 keys][64 dims]
    const int vr = tid >> 2, vcb = (tid & 3) * 32;      // V^T: [64 dims][128 keys]
    const float scl = 0.125f;

    v8bf kreg[4], vreg[4];
    {
        const bf16* ks = &Kb[(size_t)(0 * 128 + krow) * 256 + kvh * DH + kcb];
        const bf16* vs = &Vtg[(size_t)(kvh * DH + vr) * L_SEQ + 0 * 128 + vcb];
#pragma unroll
        for (int u = 0; u < 4; u++) { kreg[u] = *(const v8bf*)&ks[8 * u]; vreg[u] = *(const v8bf*)&vs[8 * u]; }
#pragma unroll
        for (int u = 0; u < 4; u++) { *(v8bf*)&Ks[krow][kcb + 8 * u] = kreg[u]; *(v8bf*)&Vt[vr][vcb + 8 * u] = vreg[u]; }
    }

    for (int kb = 0; kb <= qb; kb++) {
        __syncthreads();   // staged tile visible
        if (kb < qb) {     // prefetch next tile into registers (in flight during compute)
            const bf16* ks = &Kb[(size_t)((kb + 1) * 128 + krow) * 256 + kvh * DH + kcb];
            const bf16* vs = &Vtg[(size_t)(kvh * DH + vr) * L_SEQ + (kb + 1) * 128 + vcb];
#pragma unroll
            for (int u = 0; u < 4; u++) { kreg[u] = *(const v8bf*)&ks[8 * u]; vreg[u] = *(const v8bf*)&vs[8 * u]; }
        }

        // ---- S = Q K^T : 2 m-frags x 8 n-tiles
        f32x4 s[2][8];
#pragma unroll
        for (int n = 0; n < 8; n++) {
            v8bf b0 = *(v8bf*)&Ks[n * 16 + l16][quad * 8];
            v8bf b1 = *(v8bf*)&Ks[n * 16 + l16][32 + quad * 8];
#pragma unroll
            for (int mf = 0; mf < 2; mf++) {
                s[mf][n] = (f32x4){0.f, 0.f, 0.f, 0.f};
                s[mf][n] = __builtin_amdgcn_mfma_f32_16x16x32_bf16(qf[mf][0], b0, s[mf][n], 0, 0, 0);
                s[mf][n] = __builtin_amdgcn_mfma_f32_16x16x32_bf16(qf[mf][1], b1, s[mf][n], 0, 0, 0);
            }
        }

        // ---- scale + causal mask
        if (kb == qb) {
#pragma unroll
            for (int mf = 0; mf < 2; mf++) {
                int rbase = qb * 128 + w * 32 + mf * 16 + quad * 4;
#pragma unroll
                for (int n = 0; n < 8; n++) {
                    int colg = kb * 128 + n * 16 + l16;
#pragma unroll
                    for (int r = 0; r < 4; r++)
                        s[mf][n][r] = (colg <= rbase + r) ? s[mf][n][r] * scl : NEG_BIG;
                }
            }
        } else {
#pragma unroll
            for (int mf = 0; mf < 2; mf++)
#pragma unroll
                for (int n = 0; n < 8; n++)
#pragma unroll
                    for (int r = 0; r < 4; r++) s[mf][n][r] *= scl;
        }

        // ---- online softmax
        float mx[2][4];
#pragma unroll
        for (int mf = 0; mf < 2; mf++)
#pragma unroll
            for (int r = 0; r < 4; r++) {
                float m0 = s[mf][0][r];
#pragma unroll
                for (int n = 1; n < 8; n++) m0 = fmaxf(m0, s[mf][n][r]);
                mx[mf][r] = m0;
            }
#pragma unroll
        for (int off = 1; off < 16; off <<= 1)
#pragma unroll
            for (int mf = 0; mf < 2; mf++)
#pragma unroll
                for (int r = 0; r < 4; r++)
                    mx[mf][r] = fmaxf(mx[mf][r], __shfl_xor(mx[mf][r], off));

        float alpha[2][4], mnew[2][4], rs[2][4];
#pragma unroll
        for (int mf = 0; mf < 2; mf++)
#pragma unroll
            for (int r = 0; r < 4; r++) {
                mnew[mf][r]  = fmaxf(m_i[mf][r], mx[mf][r]);
                alpha[mf][r] = __expf(m_i[mf][r] - mnew[mf][r]);
                rs[mf][r] = 0.f;
            }
#pragma unroll
        for (int mf = 0; mf < 2; mf++)
#pragma unroll
            for (int n = 0; n < 8; n++)
#pragma unroll
                for (int r = 0; r < 4; r++) {
                    float p = __expf(s[mf][n][r] - mnew[mf][r]);
                    s[mf][n][r] = p;
                    rs[mf][r] += p;
                }
#pragma unroll
        for (int off = 1; off < 16; off <<= 1)
#pragma unroll
            for (int mf = 0; mf < 2; mf++)
#pragma unroll
                for (int r = 0; r < 4; r++) rs[mf][r] += __shfl_xor(rs[mf][r], off);
#pragma unroll
        for (int mf = 0; mf < 2; mf++)
#pragma unroll
            for (int r = 0; r < 4; r++) {
                l_i[mf][r] = l_i[mf][r] * alpha[mf][r] + rs[mf][r];
                m_i[mf][r] = mnew[mf][r];
            }
#pragma unroll
        for (int mf = 0; mf < 2; mf++)
#pragma unroll
            for (int d = 0; d < 4; d++)
#pragma unroll
                for (int r = 0; r < 4; r++) oacc[mf][d][r] *= alpha[mf][r];

        // ---- PV in two 64-key halves; Ps rows [w*32,+32) wave-private
#pragma unroll
        for (int half = 0; half < 2; half++) {
#pragma unroll
            for (int mf = 0; mf < 2; mf++)
#pragma unroll
                for (int n = 0; n < 4; n++)
#pragma unroll
                    for (int r = 0; r < 4; r++)
                        Ps[w * 32 + mf * 16 + quad * 4 + r][n * 16 + l16] =
                            (bf16)s[mf][half * 4 + n][r];
#pragma unroll
            for (int kf = 0; kf < 2; kf++) {
#pragma unroll
                for (int mf = 0; mf < 2; mf++) {
                    v8bf pa = *(v8bf*)&Ps[w * 32 + mf * 16 + l16][kf * 32 + quad * 8];
#pragma unroll
                    for (int d = 0; d < 4; d++) {
                        v8bf vb = *(v8bf*)&Vt[d * 16 + l16][half * 64 + kf * 32 + quad * 8];
                        oacc[mf][d] = __builtin_amdgcn_mfma_f32_16x16x32_bf16(pa, vb, oacc[mf][d], 0, 0, 0);
                    }
                }
            }
        }

        __syncthreads();   // all LDS reads of this tile done
        if (kb < qb) {     // write prefetched tile to LDS
#pragma unroll
            for (int u = 0; u < 4; u++) { *(v8bf*)&Ks[krow][kcb + 8 * u] = kreg[u]; *(v8bf*)&Vt[vr][vcb + 8 * u] = vreg[u]; }
        }
    }

    // ---- normalize + write
#pragma unroll
    for (int mf = 0; mf < 2; mf++)
#pragma unroll
        for (int d = 0; d < 4; d++)
#pragma unroll
            for (int r = 0; r < 4; r++) {
                int row = qb * 128 + w * 32 + mf * 16 + quad * 4 + r;
                int col = h * DH + d * 16 + l16;
                O[(size_t)row * DMODEL + col] = (bf16)(oacc[mf][d][r] / l_i[mf][r]);
            }
}

// ---------------------------------------------------------------------------
extern "C" void kernel_launch(void* const* d_in, const int* in_sizes, int n_in,
                              void* d_out, int out_size, void* d_ws, size_t ws_size,
                              hipStream_t stream) {
    const float* x  = (const float*)d_in[0];
    const float* Wq = (const float*)d_in[1];
    const float* Wk = (const float*)d_in[2];
    const float* Wv = (const float*)d_in[3];
    const float* Wo = (const float*)d_in[4];
    const int*   tp = (const int*)d_in[5];
    float* out = (float*)d_out;

    bf16* xb   = (bf16*)d_ws;                 // 4194304; reused as Attn after KV gemm
    bf16* wqb  = xb   + 4194304;              // 1048576
    bf16* wkvb = wqb  + 1048576;              // 524288
    bf16* wob  = wkvb + 524288;               // 1048576
    bf16* Qb   = wob  + 1048576;              // 4194304
    bf16* Kb   = Qb   + 4194304;              // 1048576  [4096][256]
    bf16* Vtg  = Kb   + 1048576;              // 1048576  [256][4096]
    bf16* Attn = xb;

    convert_all<<<6656, 256, 0, stream>>>(x, Wq, Wk, Wv, Wo, xb, wqb, wkvb, wob);
    // Q = x @ Wq^T with fused RoPE  (4096 x 1024)
    gemm128<1, bf16><<<dim3(8, 32), 256, 0, stream>>>(xb, wqb, Qb, DMODEL, DMODEL, tp);
    // K (RoPE, natural) + V (transposed)  (4096 x 512)
    gemm_kv<<<dim3(4, 32), 256, 0, stream>>>(xb, wkvb, Kb, Vtg, tp);
    // attention
    flash_attn4<<<dim3(L_SEQ / 128, NHEADS), 256, 0, stream>>>(Qb, Kb, Vtg, Attn);
    // out = Attn @ Wo^T -> float32
    gemm128<0, float><<<dim3(8, 32), 256, 0, stream>>>(Attn, wob, out, DMODEL, DMODEL, nullptr);
}

// Round 8
// 226.222 us; speedup vs baseline: 2.2274x; 1.1987x over previous
//
#include <hip/hip_runtime.h>
#include <hip/hip_bf16.h>
#include <math.h>

typedef __bf16 bf16;
typedef __bf16 v8bf __attribute__((ext_vector_type(8)));
typedef __bf16 v4bf __attribute__((ext_vector_type(4)));
typedef float f32x4 __attribute__((ext_vector_type(4)));

#define L_SEQ 4096
#define DMODEL 1024
#define NHEADS 16
#define DH 64
#define NEG_BIG (-1e30f)
#define LN1E4_64 0.14391156f   // ln(10000)/64

// ---------------------------------------------------------------------------
// One-shot f32 -> bf16 conversion. Layout: xb[4096*1024], wqkvb[1536*1024]
// (Wq rows 0..1023, Wk rows 1024..1279, Wv rows 1280..1535), wob[1024*1024].
// ---------------------------------------------------------------------------
__global__ void convert_all(const float* __restrict__ x, const float* __restrict__ wq,
                            const float* __restrict__ wk, const float* __restrict__ wv,
                            const float* __restrict__ wo,
                            bf16* __restrict__ xb, bf16* __restrict__ wqkvb,
                            bf16* __restrict__ wob) {
    int i = (blockIdx.x * 256 + threadIdx.x) * 4;
    const float* src;
    bf16* dst;
    if (i < 4194304)      { src = x  + i;             dst = xb    + i; }
    else if (i < 5242880) { src = wq + (i - 4194304); dst = wqkvb + (i - 4194304); }
    else if (i < 5505024) { src = wk + (i - 5242880); dst = wqkvb + 1048576 + (i - 5242880); }
    else if (i < 5767168) { src = wv + (i - 5505024); dst = wqkvb + 1310720 + (i - 5505024); }
    else                  { src = wo + (i - 5767168); dst = wob   + (i - 5767168); }
    f32x4 v = *(const f32x4*)src;
    v4bf r;
#pragma unroll
    for (int j = 0; j < 4; j++) r[j] = (bf16)v[j];
    *(v4bf*)dst = r;
}

// ---------------------------------------------------------------------------
// Fused QKV projection: C[4096][1536] = x @ [Wq;Wk;Wv]^T, 128x128 tiles,
// 512 threads (8 waves, 2 waves/SIMD), register-prefetch pipeline.
// Epilogue by column region: Q (+RoPE) -> Qb, K (+RoPE) -> Kb, V -> Vtg^T.
// ---------------------------------------------------------------------------
__global__ __launch_bounds__(512) void gemm_qkv(const bf16* __restrict__ A,
                                                const bf16* __restrict__ W,
                                                bf16* __restrict__ Qb,
                                                bf16* __restrict__ Kb,
                                                bf16* __restrict__ Vtg,
                                                const int* __restrict__ tp) {
    __shared__ bf16 As[128][68];
    __shared__ bf16 Bs[128][68];
    const int K = 1024;
    const int tid = threadIdx.x;
    const int w = tid >> 6, lane = tid & 63;
    const int quad = lane >> 4, l16 = lane & 15;
    const int wm = (w & 1) * 64, wn = (w >> 1) * 32;
    const int bm = blockIdx.y * 128, bn = blockIdx.x * 128;

    f32x4 acc[4][2];
#pragma unroll
    for (int mf = 0; mf < 4; mf++)
#pragma unroll
        for (int nf = 0; nf < 2; nf++) acc[mf][nf] = (f32x4){0.f, 0.f, 0.f, 0.f};

    const int sr = tid >> 2;          // 0..127
    const int scb = (tid & 3) * 16;   // 0,16,32,48

    v8bf pa0, pa1, pb0, pb1;
    {   // prologue: stage tile kt=0
        const bf16* ap = &A[(size_t)(bm + sr) * K + scb];
        const bf16* bp = &W[(size_t)(bn + sr) * K + scb];
        pa0 = *(const v8bf*)ap; pa1 = *(const v8bf*)(ap + 8);
        pb0 = *(const v8bf*)bp; pb1 = *(const v8bf*)(bp + 8);
        *(v8bf*)&As[sr][scb] = pa0; *(v8bf*)&As[sr][scb + 8] = pa1;
        *(v8bf*)&Bs[sr][scb] = pb0; *(v8bf*)&Bs[sr][scb + 8] = pb1;
    }

    for (int kt = 0; kt < K; kt += 64) {
        __syncthreads();
        const bool more = (kt + 64) < K;
        if (more) {
            const bf16* ap = &A[(size_t)(bm + sr) * K + kt + 64 + scb];
            const bf16* bp = &W[(size_t)(bn + sr) * K + kt + 64 + scb];
            pa0 = *(const v8bf*)ap; pa1 = *(const v8bf*)(ap + 8);
            pb0 = *(const v8bf*)bp; pb1 = *(const v8bf*)(bp + 8);
        }
#pragma unroll
        for (int kf = 0; kf < 2; kf++) {
            v8bf a[4], b[2];
#pragma unroll
            for (int mf = 0; mf < 4; mf++) a[mf] = *(v8bf*)&As[wm + mf * 16 + l16][kf * 32 + quad * 8];
#pragma unroll
            for (int nf = 0; nf < 2; nf++) b[nf] = *(v8bf*)&Bs[wn + nf * 16 + l16][kf * 32 + quad * 8];
#pragma unroll
            for (int mf = 0; mf < 4; mf++)
#pragma unroll
                for (int nf = 0; nf < 2; nf++)
                    acc[mf][nf] = __builtin_amdgcn_mfma_f32_16x16x32_bf16(a[mf], b[nf], acc[mf][nf], 0, 0, 0);
        }
        __syncthreads();
        if (more) {
            *(v8bf*)&As[sr][scb] = pa0; *(v8bf*)&As[sr][scb + 8] = pa1;
            *(v8bf*)&Bs[sr][scb] = pb0; *(v8bf*)&Bs[sr][scb + 8] = pb1;
        }
    }

    if (bn < 1024) {          // ---- Q region: RoPE, store Qb[row][col] ----
#pragma unroll
        for (int mf = 0; mf < 4; mf++) {
            int pos_[4];
#pragma unroll
            for (int r = 0; r < 4; r++) pos_[r] = tp[bm + wm + mf * 16 + quad * 4 + r];
#pragma unroll
            for (int nf = 0; nf < 2; nf++) {
                const int col = bn + wn + nf * 16 + l16;
                float fr = __expf(-(float)((col & 63) & ~1) * LN1E4_64);
#pragma unroll
                for (int r = 0; r < 4; r++) {
                    float v = acc[mf][nf][r];
                    float sn, cs;
                    __sincosf((float)pos_[r] * fr, &sn, &cs);
                    float p = __shfl_xor(v, 1);
                    float res = (l16 & 1) ? (p * sn + v * cs) : (v * cs - p * sn);
                    int row = bm + wm + mf * 16 + quad * 4 + r;
                    Qb[(size_t)row * DMODEL + col] = (bf16)res;
                }
            }
        }
    } else if (bn < 1280) {   // ---- K region: RoPE, store Kb[row][kcol] ----
#pragma unroll
        for (int mf = 0; mf < 4; mf++) {
            int pos_[4];
#pragma unroll
            for (int r = 0; r < 4; r++) pos_[r] = tp[bm + wm + mf * 16 + quad * 4 + r];
#pragma unroll
            for (int nf = 0; nf < 2; nf++) {
                const int kcol = bn - 1024 + wn + nf * 16 + l16;
                float fr = __expf(-(float)((kcol & 63) & ~1) * LN1E4_64);
#pragma unroll
                for (int r = 0; r < 4; r++) {
                    float v = acc[mf][nf][r];
                    float sn, cs;
                    __sincosf((float)pos_[r] * fr, &sn, &cs);
                    float p = __shfl_xor(v, 1);
                    float res = (l16 & 1) ? (p * sn + v * cs) : (v * cs - p * sn);
                    int row = bm + wm + mf * 16 + quad * 4 + r;
                    Kb[(size_t)row * 256 + kcol] = (bf16)res;
                }
            }
        }
    } else {                  // ---- V region: transposed store Vtg[vcol][row] ----
#pragma unroll
        for (int mf = 0; mf < 4; mf++)
#pragma unroll
            for (int nf = 0; nf < 2; nf++) {
                v4bf pk;
#pragma unroll
                for (int r = 0; r < 4; r++) pk[r] = (bf16)acc[mf][nf][r];
                int vcol = bn - 1280 + wn + nf * 16 + l16;
                int row = bm + wm + mf * 16 + quad * 4;
                *(v4bf*)&Vtg[(size_t)vcol * L_SEQ + row] = pk;
            }
    }
}

// ---------------------------------------------------------------------------
// Output projection: out[4096][1024] = Attn @ Wo^T, f32 out. Same engine.
// ---------------------------------------------------------------------------
__global__ __launch_bounds__(512) void gemm_out(const bf16* __restrict__ A,
                                                const bf16* __restrict__ W,
                                                float* __restrict__ C) {
    __shared__ bf16 As[128][68];
    __shared__ bf16 Bs[128][68];
    const int K = 1024, N = 1024;
    const int tid = threadIdx.x;
    const int w = tid >> 6, lane = tid & 63;
    const int quad = lane >> 4, l16 = lane & 15;
    const int wm = (w & 1) * 64, wn = (w >> 1) * 32;
    const int bm = blockIdx.y * 128, bn = blockIdx.x * 128;

    f32x4 acc[4][2];
#pragma unroll
    for (int mf = 0; mf < 4; mf++)
#pragma unroll
        for (int nf = 0; nf < 2; nf++) acc[mf][nf] = (f32x4){0.f, 0.f, 0.f, 0.f};

    const int sr = tid >> 2;
    const int scb = (tid & 3) * 16;

    v8bf pa0, pa1, pb0, pb1;
    {
        const bf16* ap = &A[(size_t)(bm + sr) * K + scb];
        const bf16* bp = &W[(size_t)(bn + sr) * K + scb];
        pa0 = *(const v8bf*)ap; pa1 = *(const v8bf*)(ap + 8);
        pb0 = *(const v8bf*)bp; pb1 = *(const v8bf*)(bp + 8);
        *(v8bf*)&As[sr][scb] = pa0; *(v8bf*)&As[sr][scb + 8] = pa1;
        *(v8bf*)&Bs[sr][scb] = pb0; *(v8bf*)&Bs[sr][scb + 8] = pb1;
    }

    for (int kt = 0; kt < K; kt += 64) {
        __syncthreads();
        const bool more = (kt + 64) < K;
        if (more) {
            const bf16* ap = &A[(size_t)(bm + sr) * K + kt + 64 + scb];
            const bf16* bp = &W[(size_t)(bn + sr) * K + kt + 64 + scb];
            pa0 = *(const v8bf*)ap; pa1 = *(const v8bf*)(ap + 8);
            pb0 = *(const v8bf*)bp; pb1 = *(const v8bf*)(bp + 8);
        }
#pragma unroll
        for (int kf = 0; kf < 2; kf++) {
            v8bf a[4], b[2];
#pragma unroll
            for (int mf = 0; mf < 4; mf++) a[mf] = *(v8bf*)&As[wm + mf * 16 + l16][kf * 32 + quad * 8];
#pragma unroll
            for (int nf = 0; nf < 2; nf++) b[nf] = *(v8bf*)&Bs[wn + nf * 16 + l16][kf * 32 + quad * 8];
#pragma unroll
            for (int mf = 0; mf < 4; mf++)
#pragma unroll
                for (int nf = 0; nf < 2; nf++)
                    acc[mf][nf] = __builtin_amdgcn_mfma_f32_16x16x32_bf16(a[mf], b[nf], acc[mf][nf], 0, 0, 0);
        }
        __syncthreads();
        if (more) {
            *(v8bf*)&As[sr][scb] = pa0; *(v8bf*)&As[sr][scb + 8] = pa1;
            *(v8bf*)&Bs[sr][scb] = pb0; *(v8bf*)&Bs[sr][scb + 8] = pb1;
        }
    }
#pragma unroll
    for (int mf = 0; mf < 4; mf++)
#pragma unroll
        for (int nf = 0; nf < 2; nf++)
#pragma unroll
            for (int r = 0; r < 4; r++) {
                int row = bm + wm + mf * 16 + quad * 4 + r;
                int col = bn + wn + nf * 16 + l16;
                C[(size_t)row * N + col] = acc[mf][nf][r];
            }
}

// ---------------------------------------------------------------------------
// Flash v5: split-K with exact load leveling. Block (bx, h) runs two pieces:
//   piece 0: (qb=bx,    z=0)  key-tiles [0, ceil(T/2))
//   piece 1: (qb=31-bx, z=1)  key-tiles [ceil(T/2), T)       (T = qb+1)
// Every block: exactly 16-17 BK=128 steps. Unnormalized partials (bf16 O,
// f32 m/l) per z; combined afterwards.
// ---------------------------------------------------------------------------
__global__ __launch_bounds__(256, 2) void flash5(const bf16* __restrict__ Q,
                                                 const bf16* __restrict__ Kb,
                                                 const bf16* __restrict__ Vtg,
                                                 bf16* __restrict__ O0,
                                                 bf16* __restrict__ O1,
                                                 float* __restrict__ ML) {
    __shared__ bf16 Ks[128][68];
    __shared__ bf16 Vt[64][132];
    __shared__ bf16 Ps[128][68];
    const int h = blockIdx.y, kvh = h >> 2;
    const int bx = blockIdx.x;
    const int tid = threadIdx.x;
    const int w = tid >> 6, lane = tid & 63;
    const int quad = lane >> 4, l16 = lane & 15;
    const int krow = tid >> 1, kcb = (tid & 1) * 32;
    const int vr = tid >> 2, vcb = (tid & 3) * 32;
    const float scl = 0.125f;

    for (int p = 0; p < 2; p++) {
        const int qb = p ? (31 - bx) : bx;
        const int T = qb + 1;
        const int k0 = p ? ((T + 1) >> 1) : 0;
        const int k1 = p ? T : ((T + 1) >> 1);
        bf16* Op = p ? O1 : O0;
        float* mlp = ML + (size_t)(p * NHEADS + h) * L_SEQ * 2;

        if (k0 >= k1) {   // empty piece (bx=31, p=1): zero partial
            for (int i = tid; i < 128 * 64; i += 256) {
                int rr = i >> 6, cc = i & 63;
                Op[(size_t)(qb * 128 + rr) * DMODEL + h * DH + cc] = (bf16)0.f;
            }
            if (tid < 128) {
                mlp[(qb * 128 + tid) * 2 + 0] = NEG_BIG;
                mlp[(qb * 128 + tid) * 2 + 1] = 0.f;
            }
            continue;   // block-uniform
        }

        v8bf qf[2][2];
#pragma unroll
        for (int mf = 0; mf < 2; mf++)
#pragma unroll
            for (int kf = 0; kf < 2; kf++)
                qf[mf][kf] = *(const v8bf*)&Q[(size_t)(qb * 128 + w * 32 + mf * 16 + l16) * DMODEL
                                              + h * DH + kf * 32 + quad * 8];

        f32x4 oacc[2][4];
#pragma unroll
        for (int mf = 0; mf < 2; mf++)
#pragma unroll
            for (int d = 0; d < 4; d++) oacc[mf][d] = (f32x4){0.f, 0.f, 0.f, 0.f};
        float m_i[2][4], l_i[2][4];
#pragma unroll
        for (int mf = 0; mf < 2; mf++)
#pragma unroll
            for (int r = 0; r < 4; r++) { m_i[mf][r] = NEG_BIG; l_i[mf][r] = 0.f; }

        v8bf kreg[4], vreg[4];
        {   // stage tile k0
            const bf16* ks = &Kb[(size_t)(k0 * 128 + krow) * 256 + kvh * DH + kcb];
            const bf16* vs = &Vtg[(size_t)(kvh * DH + vr) * L_SEQ + k0 * 128 + vcb];
#pragma unroll
            for (int u = 0; u < 4; u++) { kreg[u] = *(const v8bf*)&ks[8 * u]; vreg[u] = *(const v8bf*)&vs[8 * u]; }
            __syncthreads();   // prior piece's LDS reads complete
#pragma unroll
            for (int u = 0; u < 4; u++) { *(v8bf*)&Ks[krow][kcb + 8 * u] = kreg[u]; *(v8bf*)&Vt[vr][vcb + 8 * u] = vreg[u]; }
        }

        for (int kb = k0; kb < k1; kb++) {
            __syncthreads();
            if (kb + 1 < k1) {
                const bf16* ks = &Kb[(size_t)((kb + 1) * 128 + krow) * 256 + kvh * DH + kcb];
                const bf16* vs = &Vtg[(size_t)(kvh * DH + vr) * L_SEQ + (kb + 1) * 128 + vcb];
#pragma unroll
                for (int u = 0; u < 4; u++) { kreg[u] = *(const v8bf*)&ks[8 * u]; vreg[u] = *(const v8bf*)&vs[8 * u]; }
            }

            f32x4 s[2][8];
#pragma unroll
            for (int n = 0; n < 8; n++) {
                v8bf b0 = *(v8bf*)&Ks[n * 16 + l16][quad * 8];
                v8bf b1 = *(v8bf*)&Ks[n * 16 + l16][32 + quad * 8];
#pragma unroll
                for (int mf = 0; mf < 2; mf++) {
                    s[mf][n] = (f32x4){0.f, 0.f, 0.f, 0.f};
                    s[mf][n] = __builtin_amdgcn_mfma_f32_16x16x32_bf16(qf[mf][0], b0, s[mf][n], 0, 0, 0);
                    s[mf][n] = __builtin_amdgcn_mfma_f32_16x16x32_bf16(qf[mf][1], b1, s[mf][n], 0, 0, 0);
                }
            }

            if (kb == qb) {
#pragma unroll
                for (int mf = 0; mf < 2; mf++) {
                    int rbase = qb * 128 + w * 32 + mf * 16 + quad * 4;
#pragma unroll
                    for (int n = 0; n < 8; n++) {
                        int colg = kb * 128 + n * 16 + l16;
#pragma unroll
                        for (int r = 0; r < 4; r++)
                            s[mf][n][r] = (colg <= rbase + r) ? s[mf][n][r] * scl : NEG_BIG;
                    }
                }
            } else {
#pragma unroll
                for (int mf = 0; mf < 2; mf++)
#pragma unroll
                    for (int n = 0; n < 8; n++)
#pragma unroll
                        for (int r = 0; r < 4; r++) s[mf][n][r] *= scl;
            }

            float mx[2][4];
#pragma unroll
            for (int mf = 0; mf < 2; mf++)
#pragma unroll
                for (int r = 0; r < 4; r++) {
                    float m0 = s[mf][0][r];
#pragma unroll
                    for (int n = 1; n < 8; n++) m0 = fmaxf(m0, s[mf][n][r]);
                    mx[mf][r] = m0;
                }
#pragma unroll
            for (int off = 1; off < 16; off <<= 1)
#pragma unroll
                for (int mf = 0; mf < 2; mf++)
#pragma unroll
                    for (int r = 0; r < 4; r++)
                        mx[mf][r] = fmaxf(mx[mf][r], __shfl_xor(mx[mf][r], off));

            float alpha[2][4], mnew[2][4], rs[2][4];
#pragma unroll
            for (int mf = 0; mf < 2; mf++)
#pragma unroll
                for (int r = 0; r < 4; r++) {
                    mnew[mf][r]  = fmaxf(m_i[mf][r], mx[mf][r]);
                    alpha[mf][r] = __expf(m_i[mf][r] - mnew[mf][r]);
                    rs[mf][r] = 0.f;
                }
#pragma unroll
            for (int mf = 0; mf < 2; mf++)
#pragma unroll
                for (int n = 0; n < 8; n++)
#pragma unroll
                    for (int r = 0; r < 4; r++) {
                        float pv = __expf(s[mf][n][r] - mnew[mf][r]);
                        s[mf][n][r] = pv;
                        rs[mf][r] += pv;
                    }
#pragma unroll
            for (int off = 1; off < 16; off <<= 1)
#pragma unroll
                for (int mf = 0; mf < 2; mf++)
#pragma unroll
                    for (int r = 0; r < 4; r++) rs[mf][r] += __shfl_xor(rs[mf][r], off);
#pragma unroll
            for (int mf = 0; mf < 2; mf++)
#pragma unroll
                for (int r = 0; r < 4; r++) {
                    l_i[mf][r] = l_i[mf][r] * alpha[mf][r] + rs[mf][r];
                    m_i[mf][r] = mnew[mf][r];
                }
#pragma unroll
            for (int mf = 0; mf < 2; mf++)
#pragma unroll
                for (int d = 0; d < 4; d++)
#pragma unroll
                    for (int r = 0; r < 4; r++) oacc[mf][d][r] *= alpha[mf][r];

#pragma unroll
            for (int half = 0; half < 2; half++) {
#pragma unroll
                for (int mf = 0; mf < 2; mf++)
#pragma unroll
                    for (int n = 0; n < 4; n++)
#pragma unroll
                        for (int r = 0; r < 4; r++)
                            Ps[w * 32 + mf * 16 + quad * 4 + r][n * 16 + l16] =
                                (bf16)s[mf][half * 4 + n][r];
#pragma unroll
                for (int kf = 0; kf < 2; kf++) {
#pragma unroll
                    for (int mf = 0; mf < 2; mf++) {
                        v8bf pa = *(v8bf*)&Ps[w * 32 + mf * 16 + l16][kf * 32 + quad * 8];
#pragma unroll
                        for (int d = 0; d < 4; d++) {
                            v8bf vb = *(v8bf*)&Vt[d * 16 + l16][half * 64 + kf * 32 + quad * 8];
                            oacc[mf][d] = __builtin_amdgcn_mfma_f32_16x16x32_bf16(pa, vb, oacc[mf][d], 0, 0, 0);
                        }
                    }
                }
            }

            __syncthreads();
            if (kb + 1 < k1) {
#pragma unroll
                for (int u = 0; u < 4; u++) { *(v8bf*)&Ks[krow][kcb + 8 * u] = kreg[u]; *(v8bf*)&Vt[vr][vcb + 8 * u] = vreg[u]; }
            }
        }

        // ---- unnormalized partial write ----
#pragma unroll
        for (int mf = 0; mf < 2; mf++)
#pragma unroll
            for (int d = 0; d < 4; d++)
#pragma unroll
                for (int r = 0; r < 4; r++) {
                    int row = qb * 128 + w * 32 + mf * 16 + quad * 4 + r;
                    Op[(size_t)row * DMODEL + h * DH + d * 16 + l16] = (bf16)oacc[mf][d][r];
                }
        if (l16 == 0) {
#pragma unroll
            for (int mf = 0; mf < 2; mf++)
#pragma unroll
                for (int r = 0; r < 4; r++) {
                    int row = qb * 128 + w * 32 + mf * 16 + quad * 4 + r;
                    mlp[row * 2 + 0] = m_i[mf][r];
                    mlp[row * 2 + 1] = l_i[mf][r];
                }
        }
    }
}

// ---------------------------------------------------------------------------
// Combine the two split-K partials into normalized Attn (bf16).
// ---------------------------------------------------------------------------
__global__ void combine(const bf16* __restrict__ O0, const bf16* __restrict__ O1,
                        const float* __restrict__ ML, bf16* __restrict__ Attn) {
    int gid = blockIdx.x * 256 + threadIdx.x;
    int row = gid >> 8;
    int cg = (gid & 255) * 4;
    int h = cg >> 6;
    const float* ml0 = ML + ((size_t)h * L_SEQ + row) * 2;
    const float* ml1 = ML + ((size_t)(NHEADS + h) * L_SEQ + row) * 2;
    float m0 = ml0[0], l0 = ml0[1], m1 = ml1[0], l1 = ml1[1];
    float m = fmaxf(m0, m1);
    float a0 = __expf(m0 - m), a1 = __expf(m1 - m);
    float inv = 1.f / (a0 * l0 + a1 * l1);
    v4bf o0 = *(const v4bf*)&O0[(size_t)row * DMODEL + cg];
    v4bf o1 = *(const v4bf*)&O1[(size_t)row * DMODEL + cg];
    v4bf res;
#pragma unroll
    for (int j = 0; j < 4; j++)
        res[j] = (bf16)((a0 * (float)o0[j] + a1 * (float)o1[j]) * inv);
    *(v4bf*)&Attn[(size_t)row * DMODEL + cg] = res;
}

// ---------------------------------------------------------------------------
extern "C" void kernel_launch(void* const* d_in, const int* in_sizes, int n_in,
                              void* d_out, int out_size, void* d_ws, size_t ws_size,
                              hipStream_t stream) {
    const float* x  = (const float*)d_in[0];
    const float* Wq = (const float*)d_in[1];
    const float* Wk = (const float*)d_in[2];
    const float* Wv = (const float*)d_in[3];
    const float* Wo = (const float*)d_in[4];
    const int*   tp = (const int*)d_in[5];
    float* out = (float*)d_out;

    bf16*  xb    = (bf16*)d_ws;               // 4,194,304 (reused as Attn)
    bf16*  wqkvb = xb    + 4194304;           // 1,572,864
    bf16*  wob   = wqkvb + 1572864;           // 1,048,576
    bf16*  Qb    = wob   + 1048576;           // 4,194,304
    bf16*  Kb    = Qb    + 4194304;           // 1,048,576  [4096][256]
    bf16*  Vtg   = Kb    + 1048576;           // 1,048,576  [256][4096]
    float* MLf   = (float*)(Vtg + 1048576);   // 262,144 f32
    bf16*  Attn  = xb;
    bf16*  O0    = (bf16*)d_out;              // partial z=0 (bf16, 8.4 MB)
    bf16*  O1    = O0 + 4194304;              // partial z=1

    convert_all<<<6656, 256, 0, stream>>>(x, Wq, Wk, Wv, Wo, xb, wqkvb, wob);
    gemm_qkv<<<dim3(12, 32), 512, 0, stream>>>(xb, wqkvb, Qb, Kb, Vtg, tp);
    flash5<<<dim3(32, NHEADS), 256, 0, stream>>>(Qb, Kb, Vtg, O0, O1, MLf);
    combine<<<4096, 256, 0, stream>>>(O0, O1, MLf, Attn);
    gemm_out<<<dim3(8, 32), 512, 0, stream>>>(Attn, wob, out);
}